// Round 1
// baseline (582.846 us; speedup 1.0000x reference)
//
#include <hip/hip_runtime.h>
#include <hip/hip_bf16.h>
#include <stdint.h>

#define NN 8192
#define KF 512          // IN_F == OUT_F
#define ALPHA 0.2f

typedef __bf16 bf16;
typedef __bf16 bf16x4 __attribute__((ext_vector_type(4)));
typedef __bf16 bf16x8 __attribute__((ext_vector_type(8)));
typedef float  f32x4  __attribute__((ext_vector_type(4)));
typedef float  f32x16 __attribute__((ext_vector_type(16)));

// ---- workspace layout (bytes) ----
static constexpr size_t OFF_HT  = 0;                            // bf16 [128][512][64] = 8 MB (j-tiled h^T)
static constexpr size_t OFF_XB  = (size_t)8 << 20;              // bf16 [8192][512]    = 8 MB
static constexpr size_t OFF_WB  = (size_t)16 << 20;             // bf16 [512][512]     = 512 KB
static constexpr size_t OFF_SRC = OFF_WB + ((size_t)512 << 10); // f32 [8192]
static constexpr size_t OFF_DST = OFF_SRC + (size_t)NN * 4;     // f32 [8192]
static constexpr size_t OFF_GMX = OFF_DST + (size_t)NN * 4;     // u32 (encoded float max)
static constexpr size_t OFF_PRT = (size_t)17 << 20;             // f32 [2][8192][512] = 32 MB
static constexpr size_t OFF_PDN = OFF_PRT + ((size_t)32 << 20); // f32 [2][8192]

__device__ inline unsigned encf(float f) {
    unsigned u = __float_as_uint(f);
    return (u >> 31) ? ~u : (u | 0x80000000u);
}
__device__ inline float decf(unsigned e) {
    return (e >> 31) ? __uint_as_float(e ^ 0x80000000u) : __uint_as_float(~e);
}

// ---------------- kernel 0: f32 -> bf16 conversion of x and W ----------------
__global__ void k_cvt(const float* __restrict__ x, const float* __restrict__ W,
                      bf16* __restrict__ xb, bf16* __restrict__ wb) {
    const int XQ = (NN * KF) / 4;          // 1048576 float4's in x
    const int TQ = XQ + (KF * KF) / 4;     // + 65536 in W
    for (int i = blockIdx.x * blockDim.x + threadIdx.x; i < TQ;
         i += gridDim.x * blockDim.x) {
        const float4* s;
        bf16* d;
        int o;
        if (i < XQ) { s = (const float4*)x; d = xb; o = i; }
        else        { s = (const float4*)W; d = wb; o = i - XQ; }
        float4 v = s[o];
        bf16x4 b;
        b[0] = (bf16)v.x; b[1] = (bf16)v.y; b[2] = (bf16)v.z; b[3] = (bf16)v.w;
        *(bf16x4*)(d + (size_t)o * 4) = b;
    }
}

// ---------------- kernel 1: h = x @ W^T (bf16 MFMA), emit tiled h^T, src, dst, gmax ----------------
// grid 256 blocks x 128 threads (2 waves). Wave = 16 rows, all 512 cols in 4 chunks of 8 col-tiles.
__global__ __launch_bounds__(128) void k_gemm(
    const bf16* __restrict__ xb, const bf16* __restrict__ wb,
    bf16* __restrict__ hT, float* __restrict__ srcv, float* __restrict__ dstv,
    const float* __restrict__ a1, const float* __restrict__ a2,
    unsigned* __restrict__ gmx) {
    const int tid = threadIdx.x;
    const int wv = tid >> 6;
    const int l = tid & 63;
    const int i0 = blockIdx.x * 32 + wv * 16;
    const int kgrp = l >> 4;               // 0..3
    const int arow = i0 + (l & 15);

    float sp[4] = {0.f, 0.f, 0.f, 0.f};
    float dp[4] = {0.f, 0.f, 0.f, 0.f};

    for (int ch = 0; ch < 4; ++ch) {
        f32x4 acc[8];
#pragma unroll
        for (int ct = 0; ct < 8; ++ct) acc[ct] = (f32x4){0.f, 0.f, 0.f, 0.f};
#pragma unroll 4
        for (int k = 0; k < 16; ++k) {
            bf16x8 a = *(const bf16x8*)(xb + (size_t)arow * KF + k * 32 + kgrp * 8);
#pragma unroll
            for (int ct = 0; ct < 8; ++ct) {
                int c = ch * 128 + ct * 16 + (l & 15);
                bf16x8 b = *(const bf16x8*)(wb + (size_t)c * KF + k * 32 + kgrp * 8);
                acc[ct] = __builtin_amdgcn_mfma_f32_16x16x32_bf16(a, b, acc[ct], 0, 0, 0);
            }
        }
        // epilogue: C/D 16x16 layout: col = l&15, row = (l>>4)*4 + r
#pragma unroll
        for (int ct = 0; ct < 8; ++ct) {
            int c = ch * 128 + ct * 16 + (l & 15);
            float A1 = a1[c], A2 = a2[c];
            bf16x4 hb;
            int ib = i0 + kgrp * 4;
#pragma unroll
            for (int r = 0; r < 4; ++r) {
                float h = acc[ct][r];
                sp[r] += h * A1;
                dp[r] += h * A2;
                hb[r] = (bf16)h;
            }
            int jt = ib >> 6, jr = ib & 63;
            *(bf16x4*)(hT + ((size_t)jt * 512 + c) * 64 + jr) = hb;
        }
    }
    // reduce src/dst over the 16 col-lanes (xor masks < 16 stay in-group)
    float dred[4];
#pragma unroll
    for (int r = 0; r < 4; ++r) {
        float s = sp[r], d = dp[r];
#pragma unroll
        for (int m = 1; m < 16; m <<= 1) {
            s += __shfl_xor(s, m, 64);
            d += __shfl_xor(d, m, 64);
        }
        if ((l & 15) == 0) {
            int i = i0 + kgrp * 4 + r;
            srcv[i] = s;
            dstv[i] = d;
        }
        dred[r] = d;
    }
    float dm = fmaxf(fmaxf(dred[0], dred[1]), fmaxf(dred[2], dred[3]));
#pragma unroll
    for (int m = 16; m < 64; m <<= 1) dm = fmaxf(dm, __shfl_xor(dm, m, 64));
    if (l == 0) atomicMax(gmx, encf(dm));
}

// ---------------- kernel 4: fused masked-softmax @ h ----------------
// grid 256 = 128 row-tiles x 2 j-halves; 512 threads (8 waves).
// Per 64-j tile: stage h^T tile -> LDS, compute p tile -> LDS, 2x2 mfma_32x32x16 per wave.
__global__ __launch_bounds__(512) void k_attn(
    const int* __restrict__ adj, const bf16* __restrict__ hT,
    const float* __restrict__ srcv, const float* __restrict__ dstv,
    const unsigned* __restrict__ gmxe,
    float* __restrict__ part, float* __restrict__ pden) {
    __shared__ bf16 ht[512][72];   // padded: stride 144 B -> bank-floor b128 reads
    __shared__ bf16 pl[64][72];
    __shared__ float dls[64];

    const int tid = threadIdx.x;
    const int l = tid & 63;
    const int wv = tid >> 6;       // 0..7, wave owns cols wv*64..+63
    const int bid = blockIdx.x;
    const int rt = bid >> 1, js = bid & 1;
    const int i0 = rt * 64;
    const int jbase = js * 4096;

    const float gmax = decf(*gmxe);
    const int pr = tid >> 3;           // 0..63: p-phase row
    const int pj = (tid & 7) * 8;      // p-phase j offset (8 values)
    const float si = srcv[i0 + pr];
    const float t0 = si + gmax;
    const float mi = t0 > 0.f ? t0 : ALPHA * t0;   // uniform row upper bound

    if (tid < 64) dls[tid] = 0.f;

    f32x16 acc[2][2];
#pragma unroll
    for (int a = 0; a < 2; ++a)
#pragma unroll
        for (int b = 0; b < 2; ++b)
            acc[a][b] = (f32x16){0.f,0.f,0.f,0.f,0.f,0.f,0.f,0.f,0.f,0.f,0.f,0.f,0.f,0.f,0.f,0.f};

    const size_t adjrow = (size_t)(i0 + pr) * NN;
    __syncthreads();

    for (int t = 0; t < 64; ++t) {
        const int j0 = jbase + t * 64;
        // --- stage h^T tile (coalesced: tile is a contiguous 64 KB block) ---
        const bf16* gsrc = hT + (size_t)(js * 64 + t) * 512 * 64;
#pragma unroll
        for (int c = 0; c < 8; ++c) {
            int fo = (wv * 8 + c) * 512 + l * 8;   // flat element offset
            bf16x8 v = *(const bf16x8*)(gsrc + fo);
            int col = fo >> 6, jr = fo & 63;
            *(bf16x8*)(&ht[col][jr]) = v;
        }
        // --- p tile: 8 values per thread ---
        int4 av0 = *(const int4*)(adj + adjrow + j0 + pj);
        int4 av1 = *(const int4*)(adj + adjrow + j0 + pj + 4);
        float4 dv0 = *(const float4*)(dstv + j0 + pj);
        float4 dv1 = *(const float4*)(dstv + j0 + pj + 4);
        float w[8];
        {
            float e, lr;
            e = si + dv0.x; lr = e > 0.f ? e : ALPHA * e; w[0] = av0.x ? __expf(lr - mi) : 0.f;
            e = si + dv0.y; lr = e > 0.f ? e : ALPHA * e; w[1] = av0.y ? __expf(lr - mi) : 0.f;
            e = si + dv0.z; lr = e > 0.f ? e : ALPHA * e; w[2] = av0.z ? __expf(lr - mi) : 0.f;
            e = si + dv0.w; lr = e > 0.f ? e : ALPHA * e; w[3] = av0.w ? __expf(lr - mi) : 0.f;
            e = si + dv1.x; lr = e > 0.f ? e : ALPHA * e; w[4] = av1.x ? __expf(lr - mi) : 0.f;
            e = si + dv1.y; lr = e > 0.f ? e : ALPHA * e; w[5] = av1.y ? __expf(lr - mi) : 0.f;
            e = si + dv1.z; lr = e > 0.f ? e : ALPHA * e; w[6] = av1.z ? __expf(lr - mi) : 0.f;
            e = si + dv1.w; lr = e > 0.f ? e : ALPHA * e; w[7] = av1.w ? __expf(lr - mi) : 0.f;
        }
        bf16x8 pb;
        float dsum = 0.f;
#pragma unroll
        for (int q = 0; q < 8; ++q) { dsum += w[q]; pb[q] = (bf16)w[q]; }
        *(bf16x8*)(&pl[pr][pj]) = pb;
        dsum += __shfl_xor(dsum, 1, 64);
        dsum += __shfl_xor(dsum, 2, 64);
        dsum += __shfl_xor(dsum, 4, 64);
        if ((tid & 7) == 0) dls[pr] += dsum;
        __syncthreads();
        // --- mfma: A rows = l&31 (+rt*32), B cols = l&31 (+wv*64+ct*32), k = (l>>5)*8+i ---
#pragma unroll
        for (int k = 0; k < 4; ++k) {
            const int ko = k * 16 + (l >> 5) * 8;
            bf16x8 a0 = *(const bf16x8*)(&pl[(l & 31)][ko]);
            bf16x8 a1f = *(const bf16x8*)(&pl[32 + (l & 31)][ko]);
            bf16x8 b0 = *(const bf16x8*)(&ht[wv * 64 + (l & 31)][ko]);
            bf16x8 b1 = *(const bf16x8*)(&ht[wv * 64 + 32 + (l & 31)][ko]);
            acc[0][0] = __builtin_amdgcn_mfma_f32_32x32x16_bf16(a0, b0, acc[0][0], 0, 0, 0);
            acc[0][1] = __builtin_amdgcn_mfma_f32_32x32x16_bf16(a0, b1, acc[0][1], 0, 0, 0);
            acc[1][0] = __builtin_amdgcn_mfma_f32_32x32x16_bf16(a1f, b0, acc[1][0], 0, 0, 0);
            acc[1][1] = __builtin_amdgcn_mfma_f32_32x32x16_bf16(a1f, b1, acc[1][1], 0, 0, 0);
        }
        __syncthreads();
    }
    // --- epilogue: raw partial numerators + partial denominators ---
    float* pp = part + (size_t)js * NN * KF;
#pragma unroll
    for (int rr = 0; rr < 2; ++rr)
#pragma unroll
        for (int cc = 0; cc < 2; ++cc)
#pragma unroll
            for (int g = 0; g < 16; ++g) {
                int row = (g & 3) + 8 * (g >> 2) + 4 * (l >> 5);
                int i = i0 + rr * 32 + row;
                int c = wv * 64 + cc * 32 + (l & 31);
                pp[(size_t)i * KF + c] = acc[rr][cc][g];
            }
    if (tid < 64) pden[(size_t)js * NN + i0 + tid] = dls[tid];
}

// ---------------- kernel 5: combine j-halves and normalize ----------------
__global__ void k_red(const float* __restrict__ part, const float* __restrict__ pden,
                      float* __restrict__ out) {
    int idx = blockIdx.x * blockDim.x + threadIdx.x;   // one float4, total 1M
    const float4 p0 = *(const float4*)(part + (size_t)idx * 4);
    const float4 p1 = *(const float4*)(part + (size_t)NN * KF + (size_t)idx * 4);
    int i = idx >> 7;
    float inv = 1.f / (pden[i] + pden[NN + i]);
    float4 o;
    o.x = (p0.x + p1.x) * inv;
    o.y = (p0.y + p1.y) * inv;
    o.z = (p0.z + p1.z) * inv;
    o.w = (p0.w + p1.w) * inv;
    *(float4*)(out + (size_t)idx * 4) = o;
}

extern "C" void kernel_launch(void* const* d_in, const int* in_sizes, int n_in,
                              void* d_out, int out_size, void* d_ws, size_t ws_size,
                              hipStream_t stream) {
    (void)in_sizes; (void)n_in; (void)out_size; (void)ws_size;
    const float* x  = (const float*)d_in[0];
    const int* adj  = (const int*)d_in[1];
    const float* W  = (const float*)d_in[2];
    const float* a1 = (const float*)d_in[3];
    const float* a2 = (const float*)d_in[4];
    float* out = (float*)d_out;
    char* ws = (char*)d_ws;

    bf16* hT  = (bf16*)(ws + OFF_HT);
    bf16* xb  = (bf16*)(ws + OFF_XB);
    bf16* wb  = (bf16*)(ws + OFF_WB);
    float* sv = (float*)(ws + OFF_SRC);
    float* dv = (float*)(ws + OFF_DST);
    unsigned* gm = (unsigned*)(ws + OFF_GMX);
    float* part = (float*)(ws + OFF_PRT);
    float* pden = (float*)(ws + OFF_PDN);

    hipMemsetAsync(gm, 0, 4, stream);
    k_cvt<<<2048, 256, 0, stream>>>(x, W, xb, wb);
    k_gemm<<<256, 128, 0, stream>>>(xb, wb, hT, sv, dv, a1, a2, gm);
    k_attn<<<256, 512, 0, stream>>>(adj, hT, sv, dv, gm, part, pden);
    k_red<<<4096, 256, 0, stream>>>(part, pden, out);
}

// Round 2
// 507.244 us; speedup vs baseline: 1.1490x; 1.1490x over previous
//
#include <hip/hip_runtime.h>
#include <hip/hip_bf16.h>
#include <stdint.h>

#define NN 8192
#define KF 512          // IN_F == OUT_F
#define ALPHA 0.2f
#define NT 64           // j-tiles per k_attn block (64 j each, half of 8192)

typedef __bf16 bf16;
typedef __bf16 bf16x4 __attribute__((ext_vector_type(4)));
typedef __bf16 bf16x8 __attribute__((ext_vector_type(8)));
typedef float  f32x4  __attribute__((ext_vector_type(4)));
typedef float  f32x16 __attribute__((ext_vector_type(16)));

// ---- workspace layout (bytes) ---- (same 49 MB footprint as the passing v1)
static constexpr size_t OFF_HQ  = 0;                            // bf16 hQ interleaved h, 8 MB
static constexpr size_t OFF_XB  = (size_t)8 << 20;              // bf16 [8192][512] = 8 MB
static constexpr size_t OFF_WB  = (size_t)16 << 20;             // bf16 [512][512]  = 512 KB
static constexpr size_t OFF_SRC = OFF_WB + ((size_t)512 << 10); // f32 [8192]
static constexpr size_t OFF_DST = OFF_SRC + (size_t)NN * 4;     // f32 [8192]
static constexpr size_t OFF_PRT = (size_t)17 << 20;             // f32 [2][8192][512] = 32 MB
static constexpr size_t OFF_PDN = OFF_PRT + ((size_t)32 << 20); // f32 [2][8192]

// hQ layout: element (i, c) lives at ((i>>6)*8 + ((i>>3)&7))*4096 + c*8 + (i&7).
// => for fixed c, 8 consecutive i are 16B-contiguous: a 32x32x16 MFMA B-fragment
//    is ONE coalesced 16B load per lane (lanes = consecutive c).

// ---------------- kernel 0: f32 -> bf16 conversion of x and W ----------------
__global__ void k_cvt(const float* __restrict__ x, const float* __restrict__ W,
                      bf16* __restrict__ xb, bf16* __restrict__ wb) {
    const int XQ = (NN * KF) / 4;
    const int TQ = XQ + (KF * KF) / 4;
    for (int i = blockIdx.x * blockDim.x + threadIdx.x; i < TQ;
         i += gridDim.x * blockDim.x) {
        const float4* s;
        bf16* d;
        int o;
        if (i < XQ) { s = (const float4*)x; d = xb; o = i; }
        else        { s = (const float4*)W; d = wb; o = i - XQ; }
        float4 v = s[o];
        bf16x4 b;
        b[0] = (bf16)v.x; b[1] = (bf16)v.y; b[2] = (bf16)v.z; b[3] = (bf16)v.w;
        *(bf16x4*)(d + (size_t)o * 4) = b;
    }
}

// ---------------- kernel 1: h = x @ W^T, emit hQ + src/dst (atomic partial) ----
// 4096 wave-tasks: task = (row-group of 16) x (col-chunk of 64). 1024 blocks x 4 waves
// = 16 waves/CU. Frag loads direct from global (64B segments, L2-resident panels).
__global__ __launch_bounds__(256) void k_gemm(
    const bf16* __restrict__ xb, const bf16* __restrict__ wb,
    bf16* __restrict__ hQ, float* __restrict__ srcv, float* __restrict__ dstv,
    const float* __restrict__ a1, const float* __restrict__ a2) {
    const int tid = threadIdx.x;
    const int wv = tid >> 6;
    const int l = tid & 63;
    const int task = blockIdx.x * 4 + wv;       // 0..4095
    const int rg = task >> 3, cc = task & 7;
    const int i0 = rg * 16, c0 = cc * 64;
    const int lr16 = l & 15, lk = l >> 4;       // a-row lane, k-group (v1-proven mapping)

    f32x4 acc0 = {0.f,0.f,0.f,0.f}, acc1 = acc0, acc2 = acc0, acc3 = acc0;

    const bf16* ap  = xb + (size_t)(i0 + lr16) * KF + lk * 8;
    const bf16* bp0 = wb + (size_t)(c0 +  0 + lr16) * KF + lk * 8;
    const bf16* bp1 = wb + (size_t)(c0 + 16 + lr16) * KF + lk * 8;
    const bf16* bp2 = wb + (size_t)(c0 + 32 + lr16) * KF + lk * 8;
    const bf16* bp3 = wb + (size_t)(c0 + 48 + lr16) * KF + lk * 8;

#pragma unroll 4
    for (int k = 0; k < 16; ++k) {
        bf16x8 a  = *(const bf16x8*)(ap  + k * 32);
        bf16x8 b0 = *(const bf16x8*)(bp0 + k * 32);
        bf16x8 b1 = *(const bf16x8*)(bp1 + k * 32);
        bf16x8 b2 = *(const bf16x8*)(bp2 + k * 32);
        bf16x8 b3 = *(const bf16x8*)(bp3 + k * 32);
        acc0 = __builtin_amdgcn_mfma_f32_16x16x32_bf16(a, b0, acc0, 0, 0, 0);
        acc1 = __builtin_amdgcn_mfma_f32_16x16x32_bf16(a, b1, acc1, 0, 0, 0);
        acc2 = __builtin_amdgcn_mfma_f32_16x16x32_bf16(a, b2, acc2, 0, 0, 0);
        acc3 = __builtin_amdgcn_mfma_f32_16x16x32_bf16(a, b3, acc3, 0, 0, 0);
    }

    // epilogue: C/D layout col = l&15, row = (l>>4)*4 + r  (refcheck-proven in v1)
    const int ib = i0 + lk * 4;                 // 4-aligned row base
    const int jt = ib >> 6, kq = (ib >> 3) & 7, jr0 = ib & 7;   // jr0 in {0,4}
    float sr[4] = {0.f,0.f,0.f,0.f}, dr[4] = {0.f,0.f,0.f,0.f};
#pragma unroll
    for (int ct = 0; ct < 4; ++ct) {
        const f32x4 av = (ct == 0) ? acc0 : (ct == 1) ? acc1 : (ct == 2) ? acc2 : acc3;
        const int c = c0 + ct * 16 + lr16;
        const float A1 = a1[c], A2 = a2[c];
        bf16x4 hb;
#pragma unroll
        for (int r = 0; r < 4; ++r) {
            float h = av[r];
            sr[r] += h * A1;
            dr[r] += h * A2;
            hb[r] = (bf16)h;
        }
        *(bf16x4*)(hQ + ((size_t)(jt * 8 + kq) * 512 + c) * 8 + jr0) = hb;
    }
#pragma unroll
    for (int r = 0; r < 4; ++r) {
        float s = sr[r], d = dr[r];
        s += __shfl_xor(s, 1, 64); d += __shfl_xor(d, 1, 64);
        s += __shfl_xor(s, 2, 64); d += __shfl_xor(d, 2, 64);
        s += __shfl_xor(s, 4, 64); d += __shfl_xor(d, 4, 64);
        s += __shfl_xor(s, 8, 64); d += __shfl_xor(d, 8, 64);
        if (lr16 == 0) {
            atomicAdd(srcv + ib + r, s);
            atomicAdd(dstv + ib + r, d);
        }
    }
}

// ---------------- kernel 2: fused masked-softmax @ h ----------------
// 256 blocks = 128 row-tiles x 2 j-halves (XCD-clustered so each XCD's hQ slice
// is L2-sized). 512 threads / 8 waves. Per 64-j tile: p -> LDS (9.5 KB only),
// B-frags direct global->VGPR (prefetched 1 tile ahead), raw s_barrier +
// lgkmcnt(0) only => global prefetches stay in flight across barriers.
__global__ __launch_bounds__(512, 2) void k_attn(
    const int* __restrict__ adj, const bf16* __restrict__ hQ,
    const float* __restrict__ srcv, const float* __restrict__ dstv,
    float* __restrict__ part, float* __restrict__ pden) {
    __shared__ bf16 pl[64][72];    // 16B-aligned rows, bank-clean (v1-measured 0 conflicts)
    __shared__ float dls[64];

    const int tid = threadIdx.x;
    const int l = tid & 63;
    const int wv = tid >> 6;
    const int bid = blockIdx.x;
    const int xg = bid & 7, qg = bid >> 3;
    const int js = xg >> 2;              // XCDs 0-3 -> js0, 4-7 -> js1 (L2 locality)
    const int rt = qg * 4 + (xg & 3);    // 0..127
    const int i0 = rt * 64;
    const int jbase = js * 4096;

    const int pr = tid >> 3;             // p-row 0..63
    const int pj = (tid & 7) * 8;        // p-col offset
    const float si = srcv[i0 + pr];

    if (tid < 64) dls[tid] = 0.f;
    __syncthreads();

    const int lhi = l >> 5;
    const int l31 = l & 31;
    const int cA = wv * 64 + l31;        // wave owns cols wv*64..+63

    const int*   adjp = adj  + (size_t)(i0 + pr) * NN + jbase + pj;
    const float* dstp = dstv + jbase + pj;
    const bf16*  hqb  = hQ + (size_t)cA * 8;
    const size_t tq0  = (size_t)js * 512;           // (jt*8) unit base for this half

    f32x16 acc00 = {0.f}, acc01 = {0.f}, acc10 = {0.f}, acc11 = {0.f};

    // prologue: tile-0 operands into registers
    int4   adjA0 = *(const int4*)(adjp);
    int4   adjA1 = *(const int4*)(adjp + 4);
    float4 dstA0 = *(const float4*)(dstp);
    float4 dstA1 = *(const float4*)(dstp + 4);
    bf16x8 bfA[8], bfB[8];
#pragma unroll
    for (int k2 = 0; k2 < 4; ++k2) {
        bfA[k2 * 2]     = *(const bf16x8*)(hqb + (tq0 + k2 * 2 + lhi) * 4096);
        bfA[k2 * 2 + 1] = *(const bf16x8*)(hqb + (tq0 + k2 * 2 + lhi) * 4096 + 256);
    }
    int4 adjB0, adjB1;
    float4 dstB0, dstB1;

#define BODY(T, BFC, BFN, AJC0, AJC1, AJN0, AJN1, DSC0, DSC1, DSN0, DSN1)          \
    {                                                                              \
        const int t_ = (T);                                                        \
        if (t_ < NT - 1) {  /* adj prefetch: full-tile window hides HBM latency */ \
            AJN0 = *(const int4*)(adjp + (t_ + 1) * 64);                           \
            AJN1 = *(const int4*)(adjp + (t_ + 1) * 64 + 4);                       \
        }                                                                          \
        {                                                                          \
            float w0,w1,w2,w3,w4,w5,w6,w7, e;                                      \
            e = si + DSC0.x; e = e > 0.f ? e : ALPHA * e; w0 = AJC0.x ? __expf(e) : 0.f; \
            e = si + DSC0.y; e = e > 0.f ? e : ALPHA * e; w1 = AJC0.y ? __expf(e) : 0.f; \
            e = si + DSC0.z; e = e > 0.f ? e : ALPHA * e; w2 = AJC0.z ? __expf(e) : 0.f; \
            e = si + DSC0.w; e = e > 0.f ? e : ALPHA * e; w3 = AJC0.w ? __expf(e) : 0.f; \
            e = si + DSC1.x; e = e > 0.f ? e : ALPHA * e; w4 = AJC1.x ? __expf(e) : 0.f; \
            e = si + DSC1.y; e = e > 0.f ? e : ALPHA * e; w5 = AJC1.y ? __expf(e) : 0.f; \
            e = si + DSC1.z; e = e > 0.f ? e : ALPHA * e; w6 = AJC1.z ? __expf(e) : 0.f; \
            e = si + DSC1.w; e = e > 0.f ? e : ALPHA * e; w7 = AJC1.w ? __expf(e) : 0.f; \
            bf16x8 pb;                                                             \
            pb[0]=(bf16)w0; pb[1]=(bf16)w1; pb[2]=(bf16)w2; pb[3]=(bf16)w3;        \
            pb[4]=(bf16)w4; pb[5]=(bf16)w5; pb[6]=(bf16)w6; pb[7]=(bf16)w7;        \
            *(bf16x8*)(&pl[pr][pj]) = pb;                                          \
            float dsum = w0+w1+w2+w3+w4+w5+w6+w7;                                  \
            dsum += __shfl_xor(dsum, 1, 64);                                       \
            dsum += __shfl_xor(dsum, 2, 64);                                       \
            dsum += __shfl_xor(dsum, 4, 64);                                       \
            if ((tid & 7) == 0) dls[pr] += dsum;                                   \
        }                                                                          \
        asm volatile("s_waitcnt lgkmcnt(0)" ::: "memory");                         \
        __builtin_amdgcn_s_barrier();                                              \
        if (t_ < NT - 1) {  /* next tile's B-frags + dst: hidden under MFMA */     \
            const size_t tqn = tq0 + (size_t)(t_ + 1) * 8;                         \
            _Pragma("unroll")                                                      \
            for (int k2 = 0; k2 < 4; ++k2) {                                       \
                BFN[k2 * 2]     = *(const bf16x8*)(hqb + (tqn + k2 * 2 + lhi) * 4096);       \
                BFN[k2 * 2 + 1] = *(const bf16x8*)(hqb + (tqn + k2 * 2 + lhi) * 4096 + 256); \
            }                                                                      \
            DSN0 = *(const float4*)(dstp + (t_ + 1) * 64);                         \
            DSN1 = *(const float4*)(dstp + (t_ + 1) * 64 + 4);                     \
        }                                                                          \
        _Pragma("unroll")                                                          \
        for (int k = 0; k < 4; ++k) {                                              \
            const int ko = k * 16 + lhi * 8;                                       \
            bf16x8 a0  = *(const bf16x8*)(&pl[l31][ko]);                           \
            bf16x8 a1f = *(const bf16x8*)(&pl[32 + l31][ko]);                      \
            acc00 = __builtin_amdgcn_mfma_f32_32x32x16_bf16(a0,  BFC[k*2],   acc00, 0,0,0); \
            acc01 = __builtin_amdgcn_mfma_f32_32x32x16_bf16(a0,  BFC[k*2+1], acc01, 0,0,0); \
            acc10 = __builtin_amdgcn_mfma_f32_32x32x16_bf16(a1f, BFC[k*2],   acc10, 0,0,0); \
            acc11 = __builtin_amdgcn_mfma_f32_32x32x16_bf16(a1f, BFC[k*2+1], acc11, 0,0,0); \
        }                                                                          \
        asm volatile("s_waitcnt lgkmcnt(0)" ::: "memory");                         \
        __builtin_amdgcn_s_barrier();                                              \
    }

    for (int tt = 0; tt < NT / 2; ++tt) {
        BODY(2 * tt,     bfA, bfB, adjA0, adjA1, adjB0, adjB1, dstA0, dstA1, dstB0, dstB1)
        BODY(2 * tt + 1, bfB, bfA, adjB0, adjB1, adjA0, adjA1, dstB0, dstB1, dstA0, dstA1)
    }
#undef BODY

    // epilogue: partial numerators + denominators
    float* pp = part + (size_t)js * NN * KF;
#pragma unroll
    for (int g = 0; g < 16; ++g) {
        const int row = (g & 3) + 8 * (g >> 2) + 4 * lhi;
        pp[(size_t)(i0 + row) * KF + cA]           = acc00[g];
        pp[(size_t)(i0 + row) * KF + cA + 32]      = acc01[g];
        pp[(size_t)(i0 + 32 + row) * KF + cA]      = acc10[g];
        pp[(size_t)(i0 + 32 + row) * KF + cA + 32] = acc11[g];
    }
    if (tid < 64) pden[(size_t)js * NN + i0 + tid] = dls[tid];
}

// ---------------- kernel 3: combine j-halves and normalize ----------------
__global__ void k_red(const float* __restrict__ part, const float* __restrict__ pden,
                      float* __restrict__ out) {
    int idx = blockIdx.x * blockDim.x + threadIdx.x;   // one float4, total 1M
    const float4 p0 = *(const float4*)(part + (size_t)idx * 4);
    const float4 p1 = *(const float4*)(part + (size_t)NN * KF + (size_t)idx * 4);
    int i = idx >> 7;
    float inv = 1.f / (pden[i] + pden[NN + i]);
    float4 o;
    o.x = (p0.x + p1.x) * inv;
    o.y = (p0.y + p1.y) * inv;
    o.z = (p0.z + p1.z) * inv;
    o.w = (p0.w + p1.w) * inv;
    *(float4*)(out + (size_t)idx * 4) = o;
}

extern "C" void kernel_launch(void* const* d_in, const int* in_sizes, int n_in,
                              void* d_out, int out_size, void* d_ws, size_t ws_size,
                              hipStream_t stream) {
    (void)in_sizes; (void)n_in; (void)out_size; (void)ws_size;
    const float* x  = (const float*)d_in[0];
    const int* adj  = (const int*)d_in[1];
    const float* W  = (const float*)d_in[2];
    const float* a1 = (const float*)d_in[3];
    const float* a2 = (const float*)d_in[4];
    float* out = (float*)d_out;
    char* ws = (char*)d_ws;

    bf16* hQ  = (bf16*)(ws + OFF_HQ);
    bf16* xb  = (bf16*)(ws + OFF_XB);
    bf16* wb  = (bf16*)(ws + OFF_WB);
    float* sv = (float*)(ws + OFF_SRC);
    float* dv = (float*)(ws + OFF_DST);
    float* part = (float*)(ws + OFF_PRT);
    float* pden = (float*)(ws + OFF_PDN);

    hipMemsetAsync(sv, 0, (size_t)2 * NN * sizeof(float), stream);  // srcv+dstv (adjacent)
    k_cvt<<<2048, 256, 0, stream>>>(x, W, xb, wb);
    k_gemm<<<1024, 256, 0, stream>>>(xb, wb, hQ, sv, dv, a1, a2);
    k_attn<<<256, 512, 0, stream>>>(adj, hQ, sv, dv, part, pden);
    k_red<<<4096, 256, 0, stream>>>(part, pden, out);
}

// Round 3
// 472.280 us; speedup vs baseline: 1.2341x; 1.0740x over previous
//
#include <hip/hip_runtime.h>
#include <hip/hip_bf16.h>
#include <stdint.h>

#define NN 8192
#define KF 512          // IN_F == OUT_F
#define ALPHA 0.2f
#define NTT 64          // j-tiles per k_attn block (64 j each, half of 8192)

typedef __bf16 bf16;
typedef __bf16 bf16x4 __attribute__((ext_vector_type(4)));
typedef __bf16 bf16x8 __attribute__((ext_vector_type(8)));
typedef float  f32x4  __attribute__((ext_vector_type(4)));
typedef float  f32x16 __attribute__((ext_vector_type(16)));

// ---- workspace layout (bytes) ----
static constexpr size_t OFF_HQ  = 0;                            // bf16 hQ interleaved h, 8 MB
static constexpr size_t OFF_XB  = (size_t)8 << 20;              // bf16 [8192][512] = 8 MB
static constexpr size_t OFF_WB  = (size_t)16 << 20;             // bf16 [512][512]  = 512 KB
static constexpr size_t OFF_SRC = OFF_WB + ((size_t)512 << 10); // f32 [8192]
static constexpr size_t OFF_DST = OFF_SRC + (size_t)NN * 4;     // f32 [8192]
static constexpr size_t OFF_PRT = (size_t)17 << 20;             // f32 [2][8192][512] = 32 MB
static constexpr size_t OFF_PDN = OFF_PRT + ((size_t)32 << 20); // f32 [2][8192]

// hQ layout: element (i, c) lives at ((i>>6)*8 + ((i>>3)&7))*4096 + c*8 + (i&7).
// => for fixed c, 8 consecutive i are 16B-contiguous: a 32x32x16 MFMA B-fragment
//    is ONE coalesced 16B load per lane (lanes = consecutive c). [v2 refcheck-proven]

// ---------------- kernel 0: f32 -> bf16 conversion of x and W ----------------
__global__ void k_cvt(const float* __restrict__ x, const float* __restrict__ W,
                      bf16* __restrict__ xb, bf16* __restrict__ wb) {
    const int XQ = (NN * KF) / 4;
    const int TQ = XQ + (KF * KF) / 4;
    for (int i = blockIdx.x * blockDim.x + threadIdx.x; i < TQ;
         i += gridDim.x * blockDim.x) {
        const float4* s;
        bf16* d;
        int o;
        if (i < XQ) { s = (const float4*)x; d = xb; o = i; }
        else        { s = (const float4*)W; d = wb; o = i - XQ; }
        float4 v = s[o];
        bf16x4 b;
        b[0] = (bf16)v.x; b[1] = (bf16)v.y; b[2] = (bf16)v.z; b[3] = (bf16)v.w;
        *(bf16x4*)(d + (size_t)o * 4) = b;
    }
}

// ---------------- kernel 1: h = x @ W^T, emit hQ + src/dst (atomic partial) ----
// [v2, unchanged — refcheck-proven]
__global__ __launch_bounds__(256) void k_gemm(
    const bf16* __restrict__ xb, const bf16* __restrict__ wb,
    bf16* __restrict__ hQ, float* __restrict__ srcv, float* __restrict__ dstv,
    const float* __restrict__ a1, const float* __restrict__ a2) {
    const int tid = threadIdx.x;
    const int wv = tid >> 6;
    const int l = tid & 63;
    const int task = blockIdx.x * 4 + wv;       // 0..4095
    const int rg = task >> 3, cc = task & 7;
    const int i0 = rg * 16, c0 = cc * 64;
    const int lr16 = l & 15, lk = l >> 4;

    f32x4 acc0 = {0.f,0.f,0.f,0.f}, acc1 = acc0, acc2 = acc0, acc3 = acc0;

    const bf16* ap  = xb + (size_t)(i0 + lr16) * KF + lk * 8;
    const bf16* bp0 = wb + (size_t)(c0 +  0 + lr16) * KF + lk * 8;
    const bf16* bp1 = wb + (size_t)(c0 + 16 + lr16) * KF + lk * 8;
    const bf16* bp2 = wb + (size_t)(c0 + 32 + lr16) * KF + lk * 8;
    const bf16* bp3 = wb + (size_t)(c0 + 48 + lr16) * KF + lk * 8;

#pragma unroll 4
    for (int k = 0; k < 16; ++k) {
        bf16x8 a  = *(const bf16x8*)(ap  + k * 32);
        bf16x8 b0 = *(const bf16x8*)(bp0 + k * 32);
        bf16x8 b1 = *(const bf16x8*)(bp1 + k * 32);
        bf16x8 b2 = *(const bf16x8*)(bp2 + k * 32);
        bf16x8 b3 = *(const bf16x8*)(bp3 + k * 32);
        acc0 = __builtin_amdgcn_mfma_f32_16x16x32_bf16(a, b0, acc0, 0, 0, 0);
        acc1 = __builtin_amdgcn_mfma_f32_16x16x32_bf16(a, b1, acc1, 0, 0, 0);
        acc2 = __builtin_amdgcn_mfma_f32_16x16x32_bf16(a, b2, acc2, 0, 0, 0);
        acc3 = __builtin_amdgcn_mfma_f32_16x16x32_bf16(a, b3, acc3, 0, 0, 0);
    }

    const int ib = i0 + lk * 4;
    const int jt = ib >> 6, kq = (ib >> 3) & 7, jr0 = ib & 7;
    float sr[4] = {0.f,0.f,0.f,0.f}, dr[4] = {0.f,0.f,0.f,0.f};
#pragma unroll
    for (int ct = 0; ct < 4; ++ct) {
        const f32x4 av = (ct == 0) ? acc0 : (ct == 1) ? acc1 : (ct == 2) ? acc2 : acc3;
        const int c = c0 + ct * 16 + lr16;
        const float A1 = a1[c], A2 = a2[c];
        bf16x4 hb;
#pragma unroll
        for (int r = 0; r < 4; ++r) {
            float h = av[r];
            sr[r] += h * A1;
            dr[r] += h * A2;
            hb[r] = (bf16)h;
        }
        *(bf16x4*)(hQ + ((size_t)(jt * 8 + kq) * 512 + c) * 8 + jr0) = hb;
    }
#pragma unroll
    for (int r = 0; r < 4; ++r) {
        float s = sr[r], d = dr[r];
        s += __shfl_xor(s, 1, 64); d += __shfl_xor(d, 1, 64);
        s += __shfl_xor(s, 2, 64); d += __shfl_xor(d, 2, 64);
        s += __shfl_xor(s, 4, 64); d += __shfl_xor(d, 4, 64);
        s += __shfl_xor(s, 8, 64); d += __shfl_xor(d, 8, 64);
        if (lr16 == 0) {
            atomicAdd(srcv + ib + r, s);
            atomicAdd(dstv + ib + r, d);
        }
    }
}

// ---------------- kernel 2: fused masked-softmax @ h ----------------
// v3: single barrier per tile (double-buffered p-tile), NO in-loop shuffles or
// LDS-RMW (reg dacc, reduced once at end). Critical-path per tile = p-VALU +
// 1 ds_write + barrier + ds_read/MFMA; all global loads prefetched 1 tile ahead
// and in flight across the barrier.
__global__ __launch_bounds__(512) void k_attn(
    const int* __restrict__ adj, const bf16* __restrict__ hQ,
    const float* __restrict__ srcv, const float* __restrict__ dstv,
    float* __restrict__ part, float* __restrict__ pden) {
    __shared__ bf16 pl[2][64][72];   // double-buffered p-tile, bank-clean stride

    const int tid = threadIdx.x;
    const int l = tid & 63;
    const int wv = tid >> 6;
    const int bid = blockIdx.x;
    const int xg = bid & 7, qg = bid >> 3;
    const int js = xg >> 2;              // XCDs 0-3 -> js0, 4-7 -> js1 (hQ half L2-fit)
    const int rt = qg * 4 + (xg & 3);    // 0..127
    const int i0 = rt * 64;
    const int jbase = js * 4096;

    const int pr = tid >> 3;             // p-row 0..63
    const int pj = (tid & 7) * 8;        // p-col offset
    const float si = srcv[i0 + pr];

    const int lhi = l >> 5;
    const int l31 = l & 31;
    const int cA = wv * 64 + l31;        // wave owns cols wv*64..+63

    const int*   adjp = adj  + (size_t)(i0 + pr) * NN + jbase + pj;
    const float* dstp = dstv + jbase + pj;
    const bf16*  hqb  = hQ + (size_t)cA * 8;
    const size_t tq0  = (size_t)js * 512;

    f32x16 acc00 = {0.f}, acc01 = {0.f}, acc10 = {0.f}, acc11 = {0.f};
    float dacc = 0.f;

    // prologue: tile-0 operands into registers
    int4   aC0 = *(const int4*)(adjp);
    int4   aC1 = *(const int4*)(adjp + 4);
    float4 dC0 = *(const float4*)(dstp);
    float4 dC1 = *(const float4*)(dstp + 4);
    bf16x8 bf[8];
#pragma unroll
    for (int k2 = 0; k2 < 4; ++k2) {
        bf[k2 * 2]     = *(const bf16x8*)(hqb + (tq0 + k2 * 2 + lhi) * 4096);
        bf[k2 * 2 + 1] = *(const bf16x8*)(hqb + (tq0 + k2 * 2 + lhi) * 4096 + 256);
    }

    for (int t = 0; t < NTT; ++t) {
        // --- p tile: 8 values/thread, all in registers; lrelu = max(e, a*e) ---
        float w0, w1, w2, w3, w4, w5, w6, w7, e;
        e = si + dC0.x; e = fmaxf(e, ALPHA * e); w0 = aC0.x ? __expf(e) : 0.f;
        e = si + dC0.y; e = fmaxf(e, ALPHA * e); w1 = aC0.y ? __expf(e) : 0.f;
        e = si + dC0.z; e = fmaxf(e, ALPHA * e); w2 = aC0.z ? __expf(e) : 0.f;
        e = si + dC0.w; e = fmaxf(e, ALPHA * e); w3 = aC0.w ? __expf(e) : 0.f;
        e = si + dC1.x; e = fmaxf(e, ALPHA * e); w4 = aC1.x ? __expf(e) : 0.f;
        e = si + dC1.y; e = fmaxf(e, ALPHA * e); w5 = aC1.y ? __expf(e) : 0.f;
        e = si + dC1.z; e = fmaxf(e, ALPHA * e); w6 = aC1.z ? __expf(e) : 0.f;
        e = si + dC1.w; e = fmaxf(e, ALPHA * e); w7 = aC1.w ? __expf(e) : 0.f;
        bf16x8 pb;
        pb[0] = (bf16)w0; pb[1] = (bf16)w1; pb[2] = (bf16)w2; pb[3] = (bf16)w3;
        pb[4] = (bf16)w4; pb[5] = (bf16)w5; pb[6] = (bf16)w6; pb[7] = (bf16)w7;
        *(bf16x8*)(&pl[t & 1][pr][pj]) = pb;
        dacc += ((w0 + w1) + (w2 + w3)) + ((w4 + w5) + (w6 + w7));   // reg only

        // --- prefetch tile t+1 operands (in flight across the barrier) ---
        bf16x8 bn[8];
        if (t + 1 < NTT) {
            aC0 = *(const int4*)(adjp + (t + 1) * 64);
            aC1 = *(const int4*)(adjp + (t + 1) * 64 + 4);
            dC0 = *(const float4*)(dstp + (t + 1) * 64);
            dC1 = *(const float4*)(dstp + (t + 1) * 64 + 4);
            const size_t tqn = tq0 + (size_t)(t + 1) * 8;
#pragma unroll
            for (int k2 = 0; k2 < 4; ++k2) {
                bn[k2 * 2]     = *(const bf16x8*)(hqb + (tqn + k2 * 2 + lhi) * 4096);
                bn[k2 * 2 + 1] = *(const bf16x8*)(hqb + (tqn + k2 * 2 + lhi) * 4096 + 256);
            }
        }

        asm volatile("s_waitcnt lgkmcnt(0)" ::: "memory");   // drain the 1 ds_write
        __builtin_amdgcn_s_barrier();

        // --- MFMA cluster on tile t ---
        const bf16* plc = &pl[t & 1][0][0];
#pragma unroll
        for (int k = 0; k < 4; ++k) {
            const int ko = k * 16 + lhi * 8;
            bf16x8 a0  = *(const bf16x8*)(plc + l31 * 72 + ko);
            bf16x8 a1f = *(const bf16x8*)(plc + (32 + l31) * 72 + ko);
            acc00 = __builtin_amdgcn_mfma_f32_32x32x16_bf16(a0,  bf[k*2],   acc00, 0,0,0);
            acc01 = __builtin_amdgcn_mfma_f32_32x32x16_bf16(a0,  bf[k*2+1], acc01, 0,0,0);
            acc10 = __builtin_amdgcn_mfma_f32_32x32x16_bf16(a1f, bf[k*2],   acc10, 0,0,0);
            acc11 = __builtin_amdgcn_mfma_f32_32x32x16_bf16(a1f, bf[k*2+1], acc11, 0,0,0);
        }
        if (t + 1 < NTT) {
#pragma unroll
            for (int q = 0; q < 8; ++q) bf[q] = bn[q];   // static rotation
        }
    }

    // --- epilogue: partial numerators + one-shot denominator reduce ---
    float* pp = part + (size_t)js * NN * KF;
#pragma unroll
    for (int g = 0; g < 16; ++g) {
        const int row = (g & 3) + 8 * (g >> 2) + 4 * lhi;
        pp[(size_t)(i0 + row) * KF + cA]           = acc00[g];
        pp[(size_t)(i0 + row) * KF + cA + 32]      = acc01[g];
        pp[(size_t)(i0 + 32 + row) * KF + cA]      = acc10[g];
        pp[(size_t)(i0 + 32 + row) * KF + cA + 32] = acc11[g];
    }
    dacc += __shfl_xor(dacc, 1, 64);
    dacc += __shfl_xor(dacc, 2, 64);
    dacc += __shfl_xor(dacc, 4, 64);
    if ((tid & 7) == 0) pden[(size_t)js * NN + i0 + pr] = dacc;
}

// ---------------- kernel 3: combine j-halves and normalize ----------------
__global__ void k_red(const float* __restrict__ part, const float* __restrict__ pden,
                      float* __restrict__ out) {
    int idx = blockIdx.x * blockDim.x + threadIdx.x;   // one float4, total 1M
    const float4 p0 = *(const float4*)(part + (size_t)idx * 4);
    const float4 p1 = *(const float4*)(part + (size_t)NN * KF + (size_t)idx * 4);
    int i = idx >> 7;
    float inv = 1.f / (pden[i] + pden[NN + i]);
    float4 o;
    o.x = (p0.x + p1.x) * inv;
    o.y = (p0.y + p1.y) * inv;
    o.z = (p0.z + p1.z) * inv;
    o.w = (p0.w + p1.w) * inv;
    *(float4*)(out + (size_t)idx * 4) = o;
}

extern "C" void kernel_launch(void* const* d_in, const int* in_sizes, int n_in,
                              void* d_out, int out_size, void* d_ws, size_t ws_size,
                              hipStream_t stream) {
    (void)in_sizes; (void)n_in; (void)out_size; (void)ws_size;
    const float* x  = (const float*)d_in[0];
    const int* adj  = (const int*)d_in[1];
    const float* W  = (const float*)d_in[2];
    const float* a1 = (const float*)d_in[3];
    const float* a2 = (const float*)d_in[4];
    float* out = (float*)d_out;
    char* ws = (char*)d_ws;

    bf16* hQ  = (bf16*)(ws + OFF_HQ);
    bf16* xb  = (bf16*)(ws + OFF_XB);
    bf16* wb  = (bf16*)(ws + OFF_WB);
    float* sv = (float*)(ws + OFF_SRC);
    float* dv = (float*)(ws + OFF_DST);
    float* part = (float*)(ws + OFF_PRT);
    float* pden = (float*)(ws + OFF_PDN);

    hipMemsetAsync(sv, 0, (size_t)2 * NN * sizeof(float), stream);  // srcv+dstv
    k_cvt<<<2048, 256, 0, stream>>>(x, W, xb, wb);
    k_gemm<<<1024, 256, 0, stream>>>(xb, wb, hQ, sv, dv, a1, a2);
    k_attn<<<256, 512, 0, stream>>>(adj, hQ, sv, dv, part, pden);
    k_red<<<4096, 256, 0, stream>>>(part, pden, out);
}